// Round 10
// baseline (111.355 us; speedup 1.0000x reference)
//
#include <hip/hip_runtime.h>

// CurvatureLoss: B=4, N=4096, fp32.
// R10: R8 was LDS-pipe-bound (2.1M ds_read_b128 x ~12cyc = 41us ~ 44us wall).
// R9 halved ds_reads but regressed from bundled confounds (v2f dup-moves,
// 8-wave blocks). R10 = R8's exact scalar loop + 2 queries/lane:
//  - 2048 blocks x 4 waves (8192 waves, proven operating point), CHK=64/wave
//    -> ds_reads halve to 1.05M; VALU unchanged (~22M wave-inst).
//  - in-block merge scratch stores KEYS ONLY (winning wave id recovers the
//    index) -> LDS 10.3 KB -> 8 blocks/CU = full 32 waves/CU.
//  - pack folded into LDS staging: 2 dispatches.
//  - NCB=16 -> partial 10.5 MB in d_ws; R8's proven 3-kernel path kept as
//    fallback if ws_size < that.

constexpr int BB   = 4;
constexpr int NN   = 4096;
constexpr int QPG  = 128;            // queries per group/block (2 per lane)
constexpr int WPB  = 4;              // waves per block
constexpr int CHK  = 64;             // candidates per wave
constexpr int CPBL = WPB * CHK;      // 256 candidates per block
constexpr int NCB  = NN / CPBL;      // 16 chunk-blocks per group
constexpr int NGRP = BB * NN / QPG;  // 128 groups
constexpr int NBLK = NGRP * NCB;     // 2048 blocks
constexpr float NEGBIG = -3.402823466e+38f;

__device__ __forceinline__ float fmed3(float a, float b, float c) {
    return __builtin_amdgcn_fmed3f(a, b, c);
}
__device__ __forceinline__ float embed6(float t, unsigned eb) {
    return __uint_as_float((__float_as_uint(t) & 0xFFFFFFC0u) | eb);
}

// ---------------- main path ----------------

__global__ __launch_bounds__(256, 8) void knn_kernel(
    const float* __restrict__ ori, const float* __restrict__ adv,
    float* __restrict__ partial)
{
    const int tid  = threadIdx.x;
    const int lane = tid & 63;
    const int w    = tid >> 6;            // wave 0..3
    const int g    = blockIdx.x >> 4;     // group 0..127
    const int cb   = blockIdx.x & (NCB - 1);
    const int b    = g >> 5;              // batch
    const int gl   = g & 31;              // group within batch

    __shared__ __align__(16) float smem[2560];   // 10.25 KB union
    float4* tile = (float4*)smem;                // 512 float4 = 8 KB

    // this lane's two queries (load before barrier to overlap)
    const int qb0 = gl * QPG + lane;      // batch-local
    const int qb1 = qb0 + 64;
    const float* p0o = ori + ((size_t)b * NN + qb0) * 3;
    const float* p1o = ori + ((size_t)b * NN + qb1) * 3;
    const float* p0a = adv + ((size_t)b * NN + qb0) * 3;
    const float* p1a = adv + ((size_t)b * NN + qb1) * 3;
    const float qo0x = p0o[0], qo0y = p0o[1], qo0z = p0o[2];
    const float qo1x = p1o[0], qo1y = p1o[1], qo1z = p1o[2];
    const float qa0x = p0a[0], qa0y = p0a[1], qa0z = p0a[2];
    const float qa1x = p1a[0], qa1y = p1a[1], qa1z = p1a[2];

    // stage 256 candidates: raw -> {x,y,z, 0.5|c|^2} (ori,adv interleaved)
    {
        const int j = cb * CPBL + tid;    // batch-local candidate
        const float* po = ori + ((size_t)b * NN + j) * 3;
        const float* pa = adv + ((size_t)b * NN + j) * 3;
        float x = po[0], y = po[1], z = po[2];
        tile[2 * tid]     = make_float4(x, y, z, 0.5f * (x * x + y * y + z * z));
        x = pa[0]; y = pa[1]; z = pa[2];
        tile[2 * tid + 1] = make_float4(x, y, z, 0.5f * (x * x + y * y + z * z));
    }
    __syncthreads();

    // top-3 trackers (max = closest); self key guaranteed rank-1
    float oA0 = NEGBIG, oB0 = NEGBIG, oC0 = NEGBIG;
    float oA1 = NEGBIG, oB1 = NEGBIG, oC1 = NEGBIG;
    float aA0 = NEGBIG, aB0 = NEGBIG, aC0 = NEGBIG;
    float aA1 = NEGBIG, aB1 = NEGBIG, aC1 = NEGBIG;
    float m0  = NEGBIG, m1  = NEGBIG;

    const float4* tw = tile + w * (CHK * 2);

    #pragma unroll 8
    for (int t = 0; t < CHK; ++t) {
        const float4 co = tw[2 * t];          // broadcast ds_read_b128
        const float4 ca = tw[2 * t + 1];
        const unsigned eb = (unsigned)(CHK - 1 - t);  // smaller t -> larger key

        float x;
        x = fmaf(qo0z, co.z, -co.w); x = fmaf(qo0y, co.y, x); x = fmaf(qo0x, co.x, x);
        const float ko0 = embed6(x, eb);
        x = fmaf(qo1z, co.z, -co.w); x = fmaf(qo1y, co.y, x); x = fmaf(qo1x, co.x, x);
        const float ko1 = embed6(x, eb);
        x = fmaf(qa0z, co.z, -co.w); x = fmaf(qa0y, co.y, x); x = fmaf(qa0x, co.x, x);
        const float km0 = embed6(x, eb);
        x = fmaf(qa1z, co.z, -co.w); x = fmaf(qa1y, co.y, x); x = fmaf(qa1x, co.x, x);
        const float km1 = embed6(x, eb);
        x = fmaf(qa0z, ca.z, -ca.w); x = fmaf(qa0y, ca.y, x); x = fmaf(qa0x, ca.x, x);
        const float ka0 = embed6(x, eb);
        x = fmaf(qa1z, ca.z, -ca.w); x = fmaf(qa1y, ca.y, x); x = fmaf(qa1x, ca.x, x);
        const float ka1 = embed6(x, eb);

        oC0 = fmed3(oB0, oC0, ko0); oB0 = fmed3(oA0, oB0, ko0); oA0 = fmaxf(oA0, ko0);
        oC1 = fmed3(oB1, oC1, ko1); oB1 = fmed3(oA1, oB1, ko1); oA1 = fmaxf(oA1, ko1);
        aC0 = fmed3(aB0, aC0, ka0); aB0 = fmed3(aA0, aB0, ka0); aA0 = fmaxf(aA0, ka0);
        aC1 = fmed3(aB1, aC1, ka1); aB1 = fmed3(aA1, aB1, ka1); aA1 = fmaxf(aA1, ka1);
        m0  = fmaxf(m0, km0);
        m1  = fmaxf(m1, km1);
    }

    // self-collapse (wave-uniform): wave's chunk c holds q0 iff c == gl*2,
    // q1 iff c == gl*2+1  (c = cb*4 + w, batch-local chunk of 64)
    const int c = cb * WPB + w;
    if (c == gl * 2)     { oA0 = oB0; oB0 = oC0; aA0 = aB0; aB0 = aC0; }
    if (c == gl * 2 + 1) { oA1 = oB1; oB1 = oC1; aA1 = aB1; aB1 = aC1; }

    __syncthreads();                      // tile dead; reuse smem as scratch
    // scratch: [wave][query(128)][5] keys only — index recovered from
    // (key low 6 bits, winning wave) by the merging thread.
    {
        float* r0 = smem + (size_t)(w * QPG + lane) * 5;
        r0[0] = oA0; r0[1] = oB0; r0[2] = aA0; r0[3] = aB0; r0[4] = m0;
        float* r1 = smem + (size_t)(w * QPG + 64 + lane) * 5;
        r1[0] = oA1; r1[1] = oB1; r1[2] = aA1; r1[3] = aB1; r1[4] = m1;
    }
    __syncthreads();

    if (tid < QPG) {
        // merge 4 wave-records for query tid (ascending w = ascending j;
        // strict > keeps smaller global index on ties)
        const float* r = smem + (size_t)tid * 5;
        float ko0 = r[0], ko1 = r[1], ka0 = r[2], ka1 = r[3], km = r[4];
        int wo0 = 0, wo1 = 0, wa0 = 0, wa1 = 0, wm = 0;
        #pragma unroll
        for (int ww = 1; ww < WPB; ++ww) {
            const float* s = smem + (size_t)(ww * QPG + tid) * 5;
            float c0, c1;
            c0 = s[0]; c1 = s[1];
            if (c0 > ko0)      { ko1 = ko0; wo1 = wo0; ko0 = c0; wo0 = ww; }
            else if (c0 > ko1) { ko1 = c0; wo1 = ww; }
            if (c1 > ko1)      { ko1 = c1; wo1 = ww; }
            c0 = s[2]; c1 = s[3];
            if (c0 > ka0)      { ka1 = ka0; wa1 = wa0; ka0 = c0; wa0 = ww; }
            else if (c0 > ka1) { ka1 = c0; wa1 = ww; }
            if (c1 > ka1)      { ka1 = c1; wa1 = ww; }
            if (s[4] > km)     { km = s[4]; wm = ww; }
        }
        const int cbase = cb * WPB;
        const int jo0 = (cbase + wo0) * CHK + (CHK - 1 - (int)(__float_as_uint(ko0) & 63u));
        const int jo1 = (cbase + wo1) * CHK + (CHK - 1 - (int)(__float_as_uint(ko1) & 63u));
        const int ja0 = (cbase + wa0) * CHK + (CHK - 1 - (int)(__float_as_uint(ka0) & 63u));
        const int ja1 = (cbase + wa1) * CHK + (CHK - 1 - (int)(__float_as_uint(ka1) & 63u));
        const int jm  = (cbase + wm)  * CHK + (CHK - 1 - (int)(__float_as_uint(km)  & 63u));

        float* dst = partial + ((size_t)(g * QPG + tid) * NCB + cb) * 10;
        dst[0] = ko0; dst[1] = ko1; dst[2] = ka0; dst[3] = ka1; dst[4] = km;
        dst[5] = __int_as_float(jo0); dst[6] = __int_as_float(jo1);
        dst[7] = __int_as_float(ja0); dst[8] = __int_as_float(ja1);
        dst[9] = __int_as_float(jm);
    }
}

__device__ __forceinline__ float uad(const float* __restrict__ pts, int j,
                                     float px, float py, float pz,
                                     float nx, float ny, float nz) {
    const float* p = pts + (size_t)j * 3;
    const float vx = p[0] - px, vy = p[1] - py, vz = p[2] - pz;
    const float s  = vx * vx + vy * vy + vz * vz + 1e-12f;
    return fabsf((vx * nx + vy * ny + vz * nz) * (1.0f / sqrtf(s)));
}

__global__ __launch_bounds__(256) void merge_epilogue(
    const float* __restrict__ partial, const float* __restrict__ ori,
    const float* __restrict__ adv, const float* __restrict__ nrm,
    float* __restrict__ out)
{
    const int q  = blockIdx.x * 256 + threadIdx.x;   // 0..16383
    const int b  = q >> 12;
    const int qb = q & (NN - 1);

    const float* p = partial + (size_t)q * NCB * 10;
    float ko0 = p[0], ko1 = p[1], ka0 = p[2], ka1 = p[3], km = p[4];
    int jo0 = __float_as_int(p[5]), jo1 = __float_as_int(p[6]);
    int ja0 = __float_as_int(p[7]), ja1 = __float_as_int(p[8]);
    int jm  = __float_as_int(p[9]);
    #pragma unroll
    for (int cb = 1; cb < NCB; ++cb) {
        const float* r = p + cb * 10;
        float c0, c1; int j0, j1;
        c0 = r[0]; c1 = r[1]; j0 = __float_as_int(r[5]); j1 = __float_as_int(r[6]);
        if (c0 > ko0)      { ko1 = ko0; jo1 = jo0; ko0 = c0; jo0 = j0; }
        else if (c0 > ko1) { ko1 = c0; jo1 = j0; }
        if (c1 > ko1)      { ko1 = c1; jo1 = j1; }
        c0 = r[2]; c1 = r[3]; j0 = __float_as_int(r[7]); j1 = __float_as_int(r[8]);
        if (c0 > ka0)      { ka1 = ka0; ja1 = ja0; ka0 = c0; ja0 = j0; }
        else if (c0 > ka1) { ka1 = c0; ja1 = j0; }
        if (c1 > ka1)      { ka1 = c1; ja1 = j1; }
        if (r[4] > km)     { km = r[4]; jm = __float_as_int(r[9]); }
    }

    const float* ob = ori + (size_t)b * NN * 3;
    const float* ab = adv + (size_t)b * NN * 3;
    const float* nb = nrm + (size_t)b * NN * 3;

    const float qox = ob[3 * qb], qoy = ob[3 * qb + 1], qoz = ob[3 * qb + 2];
    const float qax = ab[3 * qb], qay = ab[3 * qb + 1], qaz = ab[3 * qb + 2];
    const float nx = nb[3 * qb], ny = nb[3 * qb + 1], nz = nb[3 * qb + 2];
    const float ok = 0.5f * (uad(ob, jo0, qox, qoy, qoz, nx, ny, nz) +
                             uad(ob, jo1, qox, qoy, qoz, nx, ny, nz));
    const float ax = nb[3 * jm], ay = nb[3 * jm + 1], az = nb[3 * jm + 2];
    const float ak = 0.5f * (uad(ab, ja0, qax, qay, qaz, ax, ay, az) +
                             uad(ab, ja1, qax, qay, qaz, ax, ay, az));
    const float d = ak - ok;
    float val = d * d;

    #pragma unroll
    for (int off = 32; off > 0; off >>= 1) val += __shfl_down(val, off);
    __shared__ float ls[4];
    if ((threadIdx.x & 63) == 0) ls[threadIdx.x >> 6] = val;
    __syncthreads();
    if (threadIdx.x == 0)
        atomicAdd(out, (ls[0] + ls[1] + ls[2] + ls[3]) * (1.0f / (float)(BB * NN)));
}

// ---------------- fallback path (R8 verbatim, ws too small) ----------------

constexpr int GQ_F   = 64;
constexpr int NGRP_F = BB * NN / GQ_F;       // 256
constexpr int CHK_F  = 128;
constexpr int CPBLK_F= 4;
constexpr int BPG_F  = NN / CHK_F / CPBLK_F; // 8
constexpr int NBLK_F = NGRP_F * BPG_F;       // 2048

__device__ __forceinline__ float embed7(float t, unsigned eb) {
    return __uint_as_float((__float_as_uint(t) & 0xFFFFFF80u) | eb);
}

__global__ __launch_bounds__(256) void pack2_kernel(
    const float* __restrict__ ori, const float* __restrict__ adv,
    float4* __restrict__ candP)
{
    const int i = blockIdx.x * blockDim.x + threadIdx.x;
    if (i < BB * NN) {
        float x = ori[3 * i], y = ori[3 * i + 1], z = ori[3 * i + 2];
        candP[2 * i]     = make_float4(x, y, z, 0.5f * (x * x + y * y + z * z));
        x = adv[3 * i]; y = adv[3 * i + 1]; z = adv[3 * i + 2];
        candP[2 * i + 1] = make_float4(x, y, z, 0.5f * (x * x + y * y + z * z));
    }
}

__global__ __launch_bounds__(256, 8) void knn_groups_f(
    const float4* __restrict__ candP, float* __restrict__ partial)
{
    const int tid  = threadIdx.x;
    const int lane = tid & 63;
    const int w    = tid >> 6;
    const int group= blockIdx.x >> 3;
    const int cb   = blockIdx.x & 7;
    const int b    = group >> 6;
    const int g    = group & 63;
    const int c    = cb * CPBLK_F + w;

    __shared__ float4 lds4[1024];

    {
        const float4* __restrict__ src =
            candP + ((size_t)b * NN + cb * (CPBLK_F * CHK_F)) * 2;
        #pragma unroll
        for (int u = 0; u < 4; ++u)
            lds4[tid + 256 * u] = src[tid + 256 * u];
    }

    const int qb = g * GQ_F + lane;
    const float4 qo = candP[((size_t)b * NN + qb) * 2];
    const float4 qa = candP[((size_t)b * NN + qb) * 2 + 1];
    __syncthreads();

    float oA = NEGBIG, oB = NEGBIG, oC = NEGBIG;
    float aA = NEGBIG, aB = NEGBIG, aC = NEGBIG;
    float mm = NEGBIG;

    const float4* __restrict__ tile = lds4 + w * (CHK_F * 2);

    #pragma unroll 16
    for (int t = 0; t < CHK_F; ++t) {
        const float4 co = tile[2 * t];
        const float4 ca = tile[2 * t + 1];
        const unsigned eb = (unsigned)(CHK_F - 1 - t);
        float x;
        x = fmaf(qo.z, co.z, -co.w); x = fmaf(qo.y, co.y, x); x = fmaf(qo.x, co.x, x);
        const float ko = embed7(x, eb);
        x = fmaf(qa.z, co.z, -co.w); x = fmaf(qa.y, co.y, x); x = fmaf(qa.x, co.x, x);
        const float km = embed7(x, eb);
        x = fmaf(qa.z, ca.z, -ca.w); x = fmaf(qa.y, ca.y, x); x = fmaf(qa.x, ca.x, x);
        const float ka = embed7(x, eb);
        oC = fmed3(oB, oC, ko); oB = fmed3(oA, oB, ko); oA = fmaxf(oA, ko);
        aC = fmed3(aB, aC, ka); aB = fmed3(aA, aB, ka); aA = fmaxf(aA, ka);
        mm = fmaxf(mm, km);
    }

    if ((qb >> 7) == c) { oA = oB; oB = oC; aA = aB; aB = aC; }

    const int base = c * CHK_F;
    const int io0 = base + (CHK_F - 1 - (int)(__float_as_uint(oA) & 127u));
    const int io1 = base + (CHK_F - 1 - (int)(__float_as_uint(oB) & 127u));
    const int ia0 = base + (CHK_F - 1 - (int)(__float_as_uint(aA) & 127u));
    const int ia1 = base + (CHK_F - 1 - (int)(__float_as_uint(aB) & 127u));
    const int im  = base + (CHK_F - 1 - (int)(__float_as_uint(mm) & 127u));

    __syncthreads();
    float* mg = (float*)lds4;
    {
        float* my = mg + (w * 64 + lane) * 10;
        my[0] = oA; my[1] = oB; my[2] = aA; my[3] = aB; my[4] = mm;
        my[5] = __int_as_float(io0); my[6] = __int_as_float(io1);
        my[7] = __int_as_float(ia0); my[8] = __int_as_float(ia1);
        my[9] = __int_as_float(im);
    }
    __syncthreads();

    if (w == 0) {
        const float* p = mg + lane * 10;
        float ko0 = p[0], ko1 = p[1], ka0 = p[2], ka1 = p[3], km = p[4];
        int   jo0 = __float_as_int(p[5]), jo1 = __float_as_int(p[6]);
        int   ja0 = __float_as_int(p[7]), ja1 = __float_as_int(p[8]);
        int   jm  = __float_as_int(p[9]);
        #pragma unroll
        for (int ww = 1; ww < 4; ++ww) {
            const float* r = mg + (ww * 64 + lane) * 10;
            float c0, c1; int j0, j1;
            c0 = r[0]; c1 = r[1]; j0 = __float_as_int(r[5]); j1 = __float_as_int(r[6]);
            if (c0 > ko0)      { ko1 = ko0; jo1 = jo0; ko0 = c0; jo0 = j0; }
            else if (c0 > ko1) { ko1 = c0; jo1 = j0; }
            if (c1 > ko1)      { ko1 = c1; jo1 = j1; }
            c0 = r[2]; c1 = r[3]; j0 = __float_as_int(r[7]); j1 = __float_as_int(r[8]);
            if (c0 > ka0)      { ka1 = ka0; ja1 = ja0; ka0 = c0; ja0 = j0; }
            else if (c0 > ka1) { ka1 = c0; ja1 = j0; }
            if (c1 > ka1)      { ka1 = c1; ja1 = j1; }
            if (r[4] > km)     { km = r[4]; jm = __float_as_int(r[9]); }
        }
        float* dst = partial + ((size_t)(group * GQ_F + lane) * BPG_F + cb) * 10;
        dst[0] = ko0; dst[1] = ko1; dst[2] = ka0; dst[3] = ka1; dst[4] = km;
        dst[5] = __int_as_float(jo0); dst[6] = __int_as_float(jo1);
        dst[7] = __int_as_float(ja0); dst[8] = __int_as_float(ja1);
        dst[9] = __int_as_float(jm);
    }
}

__global__ __launch_bounds__(256) void merge_epilogue_f(
    const float* __restrict__ partial, const float4* __restrict__ candP,
    const float* __restrict__ nrm, float* __restrict__ out)
{
    const int qq = blockIdx.x * 256 + threadIdx.x;
    const int b  = qq >> 12;
    const int qb = qq & 4095;

    const float* p = partial + (size_t)qq * BPG_F * 10;
    float ko0 = p[0], ko1 = p[1], ka0 = p[2], ka1 = p[3], km = p[4];
    int   jo0 = __float_as_int(p[5]), jo1 = __float_as_int(p[6]);
    int   ja0 = __float_as_int(p[7]), ja1 = __float_as_int(p[8]);
    int   jm  = __float_as_int(p[9]);
    #pragma unroll
    for (int cb = 1; cb < BPG_F; ++cb) {
        const float* r = p + cb * 10;
        float c0, c1; int j0, j1;
        c0 = r[0]; c1 = r[1]; j0 = __float_as_int(r[5]); j1 = __float_as_int(r[6]);
        if (c0 > ko0)      { ko1 = ko0; jo1 = jo0; ko0 = c0; jo0 = j0; }
        else if (c0 > ko1) { ko1 = c0; jo1 = j0; }
        if (c1 > ko1)      { ko1 = c1; jo1 = j1; }
        c0 = r[2]; c1 = r[3]; j0 = __float_as_int(r[7]); j1 = __float_as_int(r[8]);
        if (c0 > ka0)      { ka1 = ka0; ja1 = ja0; ka0 = c0; ja0 = j0; }
        else if (c0 > ka1) { ka1 = c0; ja1 = j0; }
        if (c1 > ka1)      { ka1 = c1; ja1 = j1; }
        if (r[4] > km)     { km = r[4]; jm = __float_as_int(r[9]); }
    }

    const float4* __restrict__ cbp = candP + (size_t)b * NN * 2;
    const float*  __restrict__ nb  = nrm  + (size_t)b * NN * 3;

    const float4 qo = cbp[2 * qb], qa = cbp[2 * qb + 1];
    const float nx = nb[3 * qb], ny = nb[3 * qb + 1], nz = nb[3 * qb + 2];
    auto uadp = [](const float4 c, float px, float py, float pz,
                   float nx_, float ny_, float nz_) {
        const float vx = c.x - px, vy = c.y - py, vz = c.z - pz;
        const float s  = vx * vx + vy * vy + vz * vz + 1e-12f;
        return fabsf((vx * nx_ + vy * ny_ + vz * nz_) * (1.0f / sqrtf(s)));
    };
    const float ok = 0.5f * (uadp(cbp[2 * jo0], qo.x, qo.y, qo.z, nx, ny, nz) +
                             uadp(cbp[2 * jo1], qo.x, qo.y, qo.z, nx, ny, nz));
    const float ax = nb[3 * jm], ay = nb[3 * jm + 1], az = nb[3 * jm + 2];
    const float ak = 0.5f * (uadp(cbp[2 * ja0 + 1], qa.x, qa.y, qa.z, ax, ay, az) +
                             uadp(cbp[2 * ja1 + 1], qa.x, qa.y, qa.z, ax, ay, az));
    const float d = ak - ok;
    float val = d * d;

    #pragma unroll
    for (int off = 32; off > 0; off >>= 1) val += __shfl_down(val, off);
    __shared__ float ls[4];
    if ((threadIdx.x & 63) == 0) ls[threadIdx.x >> 6] = val;
    __syncthreads();
    if (threadIdx.x == 0)
        atomicAdd(out, (ls[0] + ls[1] + ls[2] + ls[3]) * (1.0f / (float)(BB * NN)));
}

// ---------------- launch ----------------

extern "C" void kernel_launch(void* const* d_in, const int* in_sizes, int n_in,
                              void* d_out, int out_size, void* d_ws, size_t ws_size,
                              hipStream_t stream) {
    const float* ori = (const float*)d_in[0];
    const float* adv = (const float*)d_in[1];
    const float* nrm = (const float*)d_in[2];
    float* out = (float*)d_out;

    hipMemsetAsync(out, 0, sizeof(float), stream);

    const size_t needMain = (size_t)BB * NN * NCB * 10 * sizeof(float);  // 10.49 MB
    if (ws_size >= needMain) {
        float* part = (float*)d_ws;
        hipLaunchKernelGGL(knn_kernel, dim3(NBLK), dim3(256), 0, stream,
                           ori, adv, part);
        hipLaunchKernelGGL(merge_epilogue, dim3(BB * NN / 256), dim3(256), 0, stream,
                           part, ori, adv, nrm, out);
    } else {
        // R8 verbatim fallback: 512 KB candP + 5.24 MB partial (proven fit)
        float4* candP = (float4*)d_ws;
        float*  part  = (float*)((char*)d_ws + (size_t)BB * NN * 2 * sizeof(float4));
        hipLaunchKernelGGL(pack2_kernel, dim3((BB * NN + 255) / 256), dim3(256),
                           0, stream, ori, adv, candP);
        hipLaunchKernelGGL(knn_groups_f, dim3(NBLK_F), dim3(256), 0, stream,
                           candP, part);
        hipLaunchKernelGGL(merge_epilogue_f, dim3(NGRP_F * GQ_F / 256), dim3(256),
                           0, stream, part, candP, nrm, out);
    }
}

// Round 11
// 104.395 us; speedup vs baseline: 1.0667x; 1.0667x over previous
//
#include <hip/hip_runtime.h>

// CurvatureLoss: B=4, N=4096, fp32.
// R11: R10 falsified "b128-count-bound" (halving ds_reads changed nothing).
// Best fit across R8/R9/R10: time ~ max(DS_pipe, VALU)+8%, with R9/R10's
// float*->float4* cast splitting LDS loads into ds_read_b32 x4 (R8's native
// float4 array matched true-b128 accounting exactly). Fix:
//  - LDS tile declared as NATIVE float4 array -> guaranteed ds_read_b128.
//    DS/CU: 16.4k b32*5.8 ~ 95k cyc -> 4.1k b128*12 ~ 49k cyc.
//  - field-major partial layout: knn stores and merge loads both coalesced
//    (R10 merge read 640 B/thread strided -> ~19 us tail).
// Everything else = R10 (2 q/lane, 2048 blk x 4 waves, top-3 med3, 6-bit
// embed, keys-only in-block merge, 2 dispatches).

constexpr int BB   = 4;
constexpr int NN   = 4096;
constexpr int NQ   = BB * NN;        // 16384 queries
constexpr int QPG  = 128;            // queries per group/block (2 per lane)
constexpr int WPB  = 4;              // waves per block
constexpr int CHK  = 64;             // candidates per wave
constexpr int CPBL = WPB * CHK;      // 256 candidates per block
constexpr int NCB  = NN / CPBL;      // 16 chunk-blocks per group
constexpr int NGRP = NQ / QPG;       // 128 groups
constexpr int NBLK = NGRP * NCB;     // 2048 blocks
constexpr float NEGBIG = -3.402823466e+38f;

__device__ __forceinline__ float fmed3(float a, float b, float c) {
    return __builtin_amdgcn_fmed3f(a, b, c);
}
__device__ __forceinline__ float embed6(float t, unsigned eb) {
    return __uint_as_float((__float_as_uint(t) & 0xFFFFFFC0u) | eb);  // v_and_or_b32
}

// ---------------- main path ----------------

__global__ __launch_bounds__(256, 8) void knn_kernel(
    const float* __restrict__ ori, const float* __restrict__ adv,
    float* __restrict__ partial)
{
    const int tid  = threadIdx.x;
    const int lane = tid & 63;
    const int w    = tid >> 6;            // wave 0..3
    const int g    = blockIdx.x >> 4;     // group 0..127
    const int cb   = blockIdx.x & (NCB - 1);
    const int b    = g >> 5;              // batch
    const int gl   = g & 31;              // group within batch

    // NATIVE float4 shared array (10.25 KB) -> ds_read_b128 in the hot loop.
    // Scratch phase reuses it through a float* view (scalar ds ops).
    __shared__ __align__(16) float4 sbuf[640];
    float* smem = (float*)sbuf;

    // this lane's two queries
    const int qb0 = gl * QPG + lane;      // batch-local
    const int qb1 = qb0 + 64;
    const float* p0o = ori + ((size_t)b * NN + qb0) * 3;
    const float* p1o = ori + ((size_t)b * NN + qb1) * 3;
    const float* p0a = adv + ((size_t)b * NN + qb0) * 3;
    const float* p1a = adv + ((size_t)b * NN + qb1) * 3;
    const float qo0x = p0o[0], qo0y = p0o[1], qo0z = p0o[2];
    const float qo1x = p1o[0], qo1y = p1o[1], qo1z = p1o[2];
    const float qa0x = p0a[0], qa0y = p0a[1], qa0z = p0a[2];
    const float qa1x = p1a[0], qa1y = p1a[1], qa1z = p1a[2];

    // stage 256 candidates: raw -> {x,y,z, 0.5|c|^2} (ori,adv interleaved)
    {
        const int j = cb * CPBL + tid;    // batch-local candidate
        const float* po = ori + ((size_t)b * NN + j) * 3;
        const float* pa = adv + ((size_t)b * NN + j) * 3;
        float x = po[0], y = po[1], z = po[2];
        sbuf[2 * tid]     = make_float4(x, y, z, 0.5f * (x * x + y * y + z * z));
        x = pa[0]; y = pa[1]; z = pa[2];
        sbuf[2 * tid + 1] = make_float4(x, y, z, 0.5f * (x * x + y * y + z * z));
    }
    __syncthreads();

    // top-3 trackers (max = closest); self key guaranteed rank-1
    float oA0 = NEGBIG, oB0 = NEGBIG, oC0 = NEGBIG;
    float oA1 = NEGBIG, oB1 = NEGBIG, oC1 = NEGBIG;
    float aA0 = NEGBIG, aB0 = NEGBIG, aC0 = NEGBIG;
    float aA1 = NEGBIG, aB1 = NEGBIG, aC1 = NEGBIG;
    float m0  = NEGBIG, m1  = NEGBIG;

    const float4* tw = sbuf + w * (CHK * 2);

    #pragma unroll 8
    for (int t = 0; t < CHK; ++t) {
        const float4 co = tw[2 * t];          // broadcast ds_read_b128
        const float4 ca = tw[2 * t + 1];
        const unsigned eb = (unsigned)(CHK - 1 - t);  // smaller t -> larger key

        float x;
        x = fmaf(qo0z, co.z, -co.w); x = fmaf(qo0y, co.y, x); x = fmaf(qo0x, co.x, x);
        const float ko0 = embed6(x, eb);
        x = fmaf(qo1z, co.z, -co.w); x = fmaf(qo1y, co.y, x); x = fmaf(qo1x, co.x, x);
        const float ko1 = embed6(x, eb);
        x = fmaf(qa0z, co.z, -co.w); x = fmaf(qa0y, co.y, x); x = fmaf(qa0x, co.x, x);
        const float km0 = embed6(x, eb);
        x = fmaf(qa1z, co.z, -co.w); x = fmaf(qa1y, co.y, x); x = fmaf(qa1x, co.x, x);
        const float km1 = embed6(x, eb);
        x = fmaf(qa0z, ca.z, -ca.w); x = fmaf(qa0y, ca.y, x); x = fmaf(qa0x, ca.x, x);
        const float ka0 = embed6(x, eb);
        x = fmaf(qa1z, ca.z, -ca.w); x = fmaf(qa1y, ca.y, x); x = fmaf(qa1x, ca.x, x);
        const float ka1 = embed6(x, eb);

        oC0 = fmed3(oB0, oC0, ko0); oB0 = fmed3(oA0, oB0, ko0); oA0 = fmaxf(oA0, ko0);
        oC1 = fmed3(oB1, oC1, ko1); oB1 = fmed3(oA1, oB1, ko1); oA1 = fmaxf(oA1, ko1);
        aC0 = fmed3(aB0, aC0, ka0); aB0 = fmed3(aA0, aB0, ka0); aA0 = fmaxf(aA0, ka0);
        aC1 = fmed3(aB1, aC1, ka1); aB1 = fmed3(aA1, aB1, ka1); aA1 = fmaxf(aA1, ka1);
        m0  = fmaxf(m0, km0);
        m1  = fmaxf(m1, km1);
    }

    // self-collapse (wave-uniform): wave's chunk c holds q0 iff c == gl*2,
    // q1 iff c == gl*2+1  (c = cb*4 + w, batch-local chunk of 64)
    const int c = cb * WPB + w;
    if (c == gl * 2)     { oA0 = oB0; oB0 = oC0; aA0 = aB0; aB0 = aC0; }
    if (c == gl * 2 + 1) { oA1 = oB1; oB1 = oC1; aA1 = aB1; aB1 = aC1; }

    __syncthreads();                      // tile dead; reuse smem as scratch
    // scratch: [wave][query(128)][5] keys only — index recovered from
    // (key low 6 bits, winning wave) by the merging thread.
    {
        float* r0 = smem + (w * QPG + lane) * 5;
        r0[0] = oA0; r0[1] = oB0; r0[2] = aA0; r0[3] = aB0; r0[4] = m0;
        float* r1 = smem + (w * QPG + 64 + lane) * 5;
        r1[0] = oA1; r1[1] = oB1; r1[2] = aA1; r1[3] = aB1; r1[4] = m1;
    }
    __syncthreads();

    if (tid < QPG) {
        // merge 4 wave-records for query tid (ascending w = ascending j;
        // strict > keeps smaller global index on ties)
        const float* r = smem + tid * 5;
        float ko0 = r[0], ko1 = r[1], ka0 = r[2], ka1 = r[3], km = r[4];
        int wo0 = 0, wo1 = 0, wa0 = 0, wa1 = 0, wm = 0;
        #pragma unroll
        for (int ww = 1; ww < WPB; ++ww) {
            const float* s = smem + (ww * QPG + tid) * 5;
            float c0, c1;
            c0 = s[0]; c1 = s[1];
            if (c0 > ko0)      { ko1 = ko0; wo1 = wo0; ko0 = c0; wo0 = ww; }
            else if (c0 > ko1) { ko1 = c0; wo1 = ww; }
            if (c1 > ko1)      { ko1 = c1; wo1 = ww; }
            c0 = s[2]; c1 = s[3];
            if (c0 > ka0)      { ka1 = ka0; wa1 = wa0; ka0 = c0; wa0 = ww; }
            else if (c0 > ka1) { ka1 = c0; wa1 = ww; }
            if (c1 > ka1)      { ka1 = c1; wa1 = ww; }
            if (s[4] > km)     { km = s[4]; wm = ww; }
        }
        const int cbase = cb * WPB;
        const int jo0 = (cbase + wo0) * CHK + (CHK - 1 - (int)(__float_as_uint(ko0) & 63u));
        const int jo1 = (cbase + wo1) * CHK + (CHK - 1 - (int)(__float_as_uint(ko1) & 63u));
        const int ja0 = (cbase + wa0) * CHK + (CHK - 1 - (int)(__float_as_uint(ka0) & 63u));
        const int ja1 = (cbase + wa1) * CHK + (CHK - 1 - (int)(__float_as_uint(ka1) & 63u));
        const int jm  = (cbase + wm)  * CHK + (CHK - 1 - (int)(__float_as_uint(km)  & 63u));

        // field-major layout: partial[(f*NCB + cb)*NQ + q] — coalesced both
        // here (stride 4 B across tid) and in merge_epilogue (across q).
        const int qg = g * QPG + tid;
        float vals[10];
        vals[0] = ko0; vals[1] = ko1; vals[2] = ka0; vals[3] = ka1; vals[4] = km;
        vals[5] = __int_as_float(jo0); vals[6] = __int_as_float(jo1);
        vals[7] = __int_as_float(ja0); vals[8] = __int_as_float(ja1);
        vals[9] = __int_as_float(jm);
        #pragma unroll
        for (int f = 0; f < 10; ++f)
            partial[((size_t)f * NCB + cb) * NQ + qg] = vals[f];
    }
}

__device__ __forceinline__ float uad(const float* __restrict__ pts, int j,
                                     float px, float py, float pz,
                                     float nx, float ny, float nz) {
    const float* p = pts + (size_t)j * 3;
    const float vx = p[0] - px, vy = p[1] - py, vz = p[2] - pz;
    const float s  = vx * vx + vy * vy + vz * vz + 1e-12f;
    return fabsf((vx * nx + vy * ny + vz * nz) * (1.0f / sqrtf(s)));
}

__global__ __launch_bounds__(256) void merge_epilogue(
    const float* __restrict__ partial, const float* __restrict__ ori,
    const float* __restrict__ adv, const float* __restrict__ nrm,
    float* __restrict__ out)
{
    const int q  = blockIdx.x * 256 + threadIdx.x;   // 0..16383
    const int b  = q >> 12;
    const int qb = q & (NN - 1);

    float ko0 = NEGBIG, ko1 = NEGBIG, ka0 = NEGBIG, ka1 = NEGBIG, km = NEGBIG;
    int jo0 = 0, jo1 = 0, ja0 = 0, ja1 = 0, jm = 0;
    #pragma unroll
    for (int cb = 0; cb < NCB; ++cb) {
        // field-major loads: stride 4 B across the wave for every field
        const float c0 = partial[((size_t)0 * NCB + cb) * NQ + q];
        const float c1 = partial[((size_t)1 * NCB + cb) * NQ + q];
        const float d0 = partial[((size_t)2 * NCB + cb) * NQ + q];
        const float d1 = partial[((size_t)3 * NCB + cb) * NQ + q];
        const float mk = partial[((size_t)4 * NCB + cb) * NQ + q];
        const int   i0 = __float_as_int(partial[((size_t)5 * NCB + cb) * NQ + q]);
        const int   i1 = __float_as_int(partial[((size_t)6 * NCB + cb) * NQ + q]);
        const int   i2 = __float_as_int(partial[((size_t)7 * NCB + cb) * NQ + q]);
        const int   i3 = __float_as_int(partial[((size_t)8 * NCB + cb) * NQ + q]);
        const int   i4 = __float_as_int(partial[((size_t)9 * NCB + cb) * NQ + q]);

        if (c0 > ko0)      { ko1 = ko0; jo1 = jo0; ko0 = c0; jo0 = i0; }
        else if (c0 > ko1) { ko1 = c0; jo1 = i0; }
        if (c1 > ko1)      { ko1 = c1; jo1 = i1; }
        if (d0 > ka0)      { ka1 = ka0; ja1 = ja0; ka0 = d0; ja0 = i2; }
        else if (d0 > ka1) { ka1 = d0; ja1 = i2; }
        if (d1 > ka1)      { ka1 = d1; ja1 = i3; }
        if (mk > km)       { km = mk; jm = i4; }
    }

    const float* ob = ori + (size_t)b * NN * 3;
    const float* ab = adv + (size_t)b * NN * 3;
    const float* nb = nrm + (size_t)b * NN * 3;

    const float qox = ob[3 * qb], qoy = ob[3 * qb + 1], qoz = ob[3 * qb + 2];
    const float qax = ab[3 * qb], qay = ab[3 * qb + 1], qaz = ab[3 * qb + 2];
    const float nx = nb[3 * qb], ny = nb[3 * qb + 1], nz = nb[3 * qb + 2];
    const float ok = 0.5f * (uad(ob, jo0, qox, qoy, qoz, nx, ny, nz) +
                             uad(ob, jo1, qox, qoy, qoz, nx, ny, nz));
    const float ax = nb[3 * jm], ay = nb[3 * jm + 1], az = nb[3 * jm + 2];
    const float ak = 0.5f * (uad(ab, ja0, qax, qay, qaz, ax, ay, az) +
                             uad(ab, ja1, qax, qay, qaz, ax, ay, az));
    const float d = ak - ok;
    float val = d * d;

    #pragma unroll
    for (int off = 32; off > 0; off >>= 1) val += __shfl_down(val, off);
    __shared__ float ls[4];
    if ((threadIdx.x & 63) == 0) ls[threadIdx.x >> 6] = val;
    __syncthreads();
    if (threadIdx.x == 0)
        atomicAdd(out, (ls[0] + ls[1] + ls[2] + ls[3]) * (1.0f / (float)(BB * NN)));
}

// ---------------- fallback path (R8 verbatim, ws too small; not expected
// to run — ws >= 10.49 MB proven by R10) ----------------

constexpr int GQ_F   = 64;
constexpr int NGRP_F = BB * NN / GQ_F;       // 256
constexpr int CHK_F  = 128;
constexpr int CPBLK_F= 4;
constexpr int BPG_F  = NN / CHK_F / CPBLK_F; // 8
constexpr int NBLK_F = NGRP_F * BPG_F;       // 2048

__device__ __forceinline__ float embed7(float t, unsigned eb) {
    return __uint_as_float((__float_as_uint(t) & 0xFFFFFF80u) | eb);
}

__global__ __launch_bounds__(256) void pack2_kernel(
    const float* __restrict__ ori, const float* __restrict__ adv,
    float4* __restrict__ candP)
{
    const int i = blockIdx.x * blockDim.x + threadIdx.x;
    if (i < BB * NN) {
        float x = ori[3 * i], y = ori[3 * i + 1], z = ori[3 * i + 2];
        candP[2 * i]     = make_float4(x, y, z, 0.5f * (x * x + y * y + z * z));
        x = adv[3 * i]; y = adv[3 * i + 1]; z = adv[3 * i + 2];
        candP[2 * i + 1] = make_float4(x, y, z, 0.5f * (x * x + y * y + z * z));
    }
}

__global__ __launch_bounds__(256, 8) void knn_groups_f(
    const float4* __restrict__ candP, float* __restrict__ partial)
{
    const int tid  = threadIdx.x;
    const int lane = tid & 63;
    const int w    = tid >> 6;
    const int group= blockIdx.x >> 3;
    const int cb   = blockIdx.x & 7;
    const int b    = group >> 6;
    const int g    = group & 63;
    const int c    = cb * CPBLK_F + w;

    __shared__ float4 lds4[1024];

    {
        const float4* __restrict__ src =
            candP + ((size_t)b * NN + cb * (CPBLK_F * CHK_F)) * 2;
        #pragma unroll
        for (int u = 0; u < 4; ++u)
            lds4[tid + 256 * u] = src[tid + 256 * u];
    }

    const int qb = g * GQ_F + lane;
    const float4 qo = candP[((size_t)b * NN + qb) * 2];
    const float4 qa = candP[((size_t)b * NN + qb) * 2 + 1];
    __syncthreads();

    float oA = NEGBIG, oB = NEGBIG, oC = NEGBIG;
    float aA = NEGBIG, aB = NEGBIG, aC = NEGBIG;
    float mm = NEGBIG;

    const float4* __restrict__ tile = lds4 + w * (CHK_F * 2);

    #pragma unroll 16
    for (int t = 0; t < CHK_F; ++t) {
        const float4 co = tile[2 * t];
        const float4 ca = tile[2 * t + 1];
        const unsigned eb = (unsigned)(CHK_F - 1 - t);
        float x;
        x = fmaf(qo.z, co.z, -co.w); x = fmaf(qo.y, co.y, x); x = fmaf(qo.x, co.x, x);
        const float ko = embed7(x, eb);
        x = fmaf(qa.z, co.z, -co.w); x = fmaf(qa.y, co.y, x); x = fmaf(qa.x, co.x, x);
        const float km = embed7(x, eb);
        x = fmaf(qa.z, ca.z, -ca.w); x = fmaf(qa.y, ca.y, x); x = fmaf(qa.x, ca.x, x);
        const float ka = embed7(x, eb);
        oC = fmed3(oB, oC, ko); oB = fmed3(oA, oB, ko); oA = fmaxf(oA, ko);
        aC = fmed3(aB, aC, ka); aB = fmed3(aA, aB, ka); aA = fmaxf(aA, ka);
        mm = fmaxf(mm, km);
    }

    if ((qb >> 7) == c) { oA = oB; oB = oC; aA = aB; aB = aC; }

    const int base = c * CHK_F;
    const int io0 = base + (CHK_F - 1 - (int)(__float_as_uint(oA) & 127u));
    const int io1 = base + (CHK_F - 1 - (int)(__float_as_uint(oB) & 127u));
    const int ia0 = base + (CHK_F - 1 - (int)(__float_as_uint(aA) & 127u));
    const int ia1 = base + (CHK_F - 1 - (int)(__float_as_uint(aB) & 127u));
    const int im  = base + (CHK_F - 1 - (int)(__float_as_uint(mm) & 127u));

    __syncthreads();
    float* mg = (float*)lds4;
    {
        float* my = mg + (w * 64 + lane) * 10;
        my[0] = oA; my[1] = oB; my[2] = aA; my[3] = aB; my[4] = mm;
        my[5] = __int_as_float(io0); my[6] = __int_as_float(io1);
        my[7] = __int_as_float(ia0); my[8] = __int_as_float(ia1);
        my[9] = __int_as_float(im);
    }
    __syncthreads();

    if (w == 0) {
        const float* p = mg + lane * 10;
        float ko0 = p[0], ko1 = p[1], ka0 = p[2], ka1 = p[3], km = p[4];
        int   jo0 = __float_as_int(p[5]), jo1 = __float_as_int(p[6]);
        int   ja0 = __float_as_int(p[7]), ja1 = __float_as_int(p[8]);
        int   jm  = __float_as_int(p[9]);
        #pragma unroll
        for (int ww = 1; ww < 4; ++ww) {
            const float* r = mg + (ww * 64 + lane) * 10;
            float c0, c1; int j0, j1;
            c0 = r[0]; c1 = r[1]; j0 = __float_as_int(r[5]); j1 = __float_as_int(r[6]);
            if (c0 > ko0)      { ko1 = ko0; jo1 = jo0; ko0 = c0; jo0 = j0; }
            else if (c0 > ko1) { ko1 = c0; jo1 = j0; }
            if (c1 > ko1)      { ko1 = c1; jo1 = j1; }
            c0 = r[2]; c1 = r[3]; j0 = __float_as_int(r[7]); j1 = __float_as_int(r[8]);
            if (c0 > ka0)      { ka1 = ka0; ja1 = ja0; ka0 = c0; ja0 = j0; }
            else if (c0 > ka1) { ka1 = c0; ja1 = j0; }
            if (c1 > ka1)      { ka1 = c1; ja1 = j1; }
            if (r[4] > km)     { km = r[4]; jm = __float_as_int(r[9]); }
        }
        float* dst = partial + ((size_t)(group * GQ_F + lane) * BPG_F + cb) * 10;
        dst[0] = ko0; dst[1] = ko1; dst[2] = ka0; dst[3] = ka1; dst[4] = km;
        dst[5] = __int_as_float(jo0); dst[6] = __int_as_float(jo1);
        dst[7] = __int_as_float(ja0); dst[8] = __int_as_float(ja1);
        dst[9] = __int_as_float(jm);
    }
}

__global__ __launch_bounds__(256) void merge_epilogue_f(
    const float* __restrict__ partial, const float4* __restrict__ candP,
    const float* __restrict__ nrm, float* __restrict__ out)
{
    const int qq = blockIdx.x * 256 + threadIdx.x;
    const int b  = qq >> 12;
    const int qb = qq & 4095;

    const float* p = partial + (size_t)qq * BPG_F * 10;
    float ko0 = p[0], ko1 = p[1], ka0 = p[2], ka1 = p[3], km = p[4];
    int   jo0 = __float_as_int(p[5]), jo1 = __float_as_int(p[6]);
    int   ja0 = __float_as_int(p[7]), ja1 = __float_as_int(p[8]);
    int   jm  = __float_as_int(p[9]);
    #pragma unroll
    for (int cb = 1; cb < BPG_F; ++cb) {
        const float* r = p + cb * 10;
        float c0, c1; int j0, j1;
        c0 = r[0]; c1 = r[1]; j0 = __float_as_int(r[5]); j1 = __float_as_int(r[6]);
        if (c0 > ko0)      { ko1 = ko0; jo1 = jo0; ko0 = c0; jo0 = j0; }
        else if (c0 > ko1) { ko1 = c0; jo1 = j0; }
        if (c1 > ko1)      { ko1 = c1; jo1 = j1; }
        c0 = r[2]; c1 = r[3]; j0 = __float_as_int(r[7]); j1 = __float_as_int(r[8]);
        if (c0 > ka0)      { ka1 = ka0; ja1 = ja0; ka0 = c0; ja0 = j0; }
        else if (c0 > ka1) { ka1 = c0; ja1 = j0; }
        if (c1 > ka1)      { ka1 = c1; ja1 = j1; }
        if (r[4] > km)     { km = r[4]; jm = __float_as_int(r[9]); }
    }

    const float4* __restrict__ cbp = candP + (size_t)b * NN * 2;
    const float*  __restrict__ nb  = nrm  + (size_t)b * NN * 3;

    const float4 qo = cbp[2 * qb], qa = cbp[2 * qb + 1];
    const float nx = nb[3 * qb], ny = nb[3 * qb + 1], nz = nb[3 * qb + 2];
    auto uadp = [](const float4 c, float px, float py, float pz,
                   float nx_, float ny_, float nz_) {
        const float vx = c.x - px, vy = c.y - py, vz = c.z - pz;
        const float s  = vx * vx + vy * vy + vz * vz + 1e-12f;
        return fabsf((vx * nx_ + vy * ny_ + vz * nz_) * (1.0f / sqrtf(s)));
    };
    const float ok = 0.5f * (uadp(cbp[2 * jo0], qo.x, qo.y, qo.z, nx, ny, nz) +
                             uadp(cbp[2 * jo1], qo.x, qo.y, qo.z, nx, ny, nz));
    const float ax = nb[3 * jm], ay = nb[3 * jm + 1], az = nb[3 * jm + 2];
    const float ak = 0.5f * (uadp(cbp[2 * ja0 + 1], qa.x, qa.y, qa.z, ax, ay, az) +
                             uadp(cbp[2 * ja1 + 1], qa.x, qa.y, qa.z, ax, ay, az));
    const float d = ak - ok;
    float val = d * d;

    #pragma unroll
    for (int off = 32; off > 0; off >>= 1) val += __shfl_down(val, off);
    __shared__ float ls[4];
    if ((threadIdx.x & 63) == 0) ls[threadIdx.x >> 6] = val;
    __syncthreads();
    if (threadIdx.x == 0)
        atomicAdd(out, (ls[0] + ls[1] + ls[2] + ls[3]) * (1.0f / (float)(BB * NN)));
}

// ---------------- launch ----------------

extern "C" void kernel_launch(void* const* d_in, const int* in_sizes, int n_in,
                              void* d_out, int out_size, void* d_ws, size_t ws_size,
                              hipStream_t stream) {
    const float* ori = (const float*)d_in[0];
    const float* adv = (const float*)d_in[1];
    const float* nrm = (const float*)d_in[2];
    float* out = (float*)d_out;

    hipMemsetAsync(out, 0, sizeof(float), stream);

    const size_t needMain = (size_t)10 * NCB * NQ * sizeof(float);  // 10.49 MB
    if (ws_size >= needMain) {
        float* part = (float*)d_ws;
        hipLaunchKernelGGL(knn_kernel, dim3(NBLK), dim3(256), 0, stream,
                           ori, adv, part);
        hipLaunchKernelGGL(merge_epilogue, dim3(NQ / 256), dim3(256), 0, stream,
                           part, ori, adv, nrm, out);
    } else {
        // R8 verbatim fallback: 512 KB candP + 5.24 MB partial (proven fit)
        float4* candP = (float4*)d_ws;
        float*  part  = (float*)((char*)d_ws + (size_t)BB * NN * 2 * sizeof(float4));
        hipLaunchKernelGGL(pack2_kernel, dim3((BB * NN + 255) / 256), dim3(256),
                           0, stream, ori, adv, candP);
        hipLaunchKernelGGL(knn_groups_f, dim3(NBLK_F), dim3(256), 0, stream,
                           candP, part);
        hipLaunchKernelGGL(merge_epilogue_f, dim3(NGRP_F * GQ_F / 256), dim3(256),
                           0, stream, part, candP, nrm, out);
    }
}